// Round 1
// baseline (918.347 us; speedup 1.0000x reference)
//
#include <hip/hip_runtime.h>
#include <math.h>

#define N_DIM 128
#define D_DIM 256
#define NH 8
#define DKH 32
#define M_ROWS (N_DIM * N_DIM) // 16384

// ---------------------------------------------------------------------------
// C[M][256] = A[M][256] @ W[256][256]^T   (W row-major [out][in], B^T layout)
// 128x128 tile, 256 threads, 8x8 microtile, BK=16.
// ---------------------------------------------------------------------------
__global__ __launch_bounds__(256) void gemm_bt_kernel(const float* __restrict__ A,
                                                      const float* __restrict__ W,
                                                      float* __restrict__ C) {
    __shared__ alignas(16) float As[16][132];
    __shared__ alignas(16) float Bs[16][132];
    const int tid = threadIdx.x;
    const int row0 = blockIdx.x * 128;
    const int col0 = blockIdx.y * 128;
    const int tx = tid & 15;   // n dir
    const int ty = tid >> 4;   // m dir

    float acc[8][8];
#pragma unroll
    for (int i = 0; i < 8; i++)
#pragma unroll
        for (int j = 0; j < 8; j++) acc[i][j] = 0.0f;

    for (int k0 = 0; k0 < 256; k0 += 16) {
#pragma unroll
        for (int e = 0; e < 2; e++) {
            int idx = tid * 2 + e;         // 0..511
            int m = idx >> 2;              // 0..127
            int k4 = (idx & 3) * 4;        // 0,4,8,12
            float4 va = *(const float4*)(A + (size_t)(row0 + m) * 256 + k0 + k4);
            As[k4 + 0][m] = va.x; As[k4 + 1][m] = va.y;
            As[k4 + 2][m] = va.z; As[k4 + 3][m] = va.w;
            float4 vb = *(const float4*)(W + (size_t)(col0 + m) * 256 + k0 + k4);
            Bs[k4 + 0][m] = vb.x; Bs[k4 + 1][m] = vb.y;
            Bs[k4 + 2][m] = vb.z; Bs[k4 + 3][m] = vb.w;
        }
        __syncthreads();
#pragma unroll
        for (int k = 0; k < 16; k++) {
            float a[8], b[8];
            *(float4*)&a[0] = *(const float4*)&As[k][ty * 8];
            *(float4*)&a[4] = *(const float4*)&As[k][ty * 8 + 4];
            *(float4*)&b[0] = *(const float4*)&Bs[k][tx * 8];
            *(float4*)&b[4] = *(const float4*)&Bs[k][tx * 8 + 4];
#pragma unroll
            for (int i = 0; i < 8; i++)
#pragma unroll
                for (int j = 0; j < 8; j++) acc[i][j] += a[i] * b[j];
        }
        __syncthreads();
    }

#pragma unroll
    for (int i = 0; i < 8; i++) {
        float* cp = C + (size_t)(row0 + ty * 8 + i) * 256 + col0 + tx * 8;
        *(float4*)cp       = make_float4(acc[i][0], acc[i][1], acc[i][2], acc[i][3]);
        *(float4*)(cp + 4) = make_float4(acc[i][4], acc[i][5], acc[i][6], acc[i][7]);
    }
}

// ---------------------------------------------------------------------------
// Attention: one block (256 threads) per (x,y) pair.
//   scores_r[x,y,z,h] = q[x,y,h,:] . k[x,z,h,:] * scale   (z = 0..127)
//   scores_l[x,y,z,h] = q[x,y,h,:] . k[z,y,h,:] * scale   (z = 0..127)
//   mask[x,y,z] (True -> -1e9) applied to BOTH halves, softmax over 256,
//   x_out[x,y,h,d] = sum_z att_r*v[x,z,h,d] + att_l*v[z,y,h,d]
// ---------------------------------------------------------------------------
__global__ __launch_bounds__(256) void attn_kernel(const float* __restrict__ q,
                                                   const float* __restrict__ k,
                                                   const float* __restrict__ v,
                                                   const int* __restrict__ mask,
                                                   float* __restrict__ xb) {
    __shared__ alignas(16) float qs[256];
    __shared__ float sc[NH][256];
    const int tid = threadIdx.x;
    const int bid = blockIdx.x;
    const int xi = bid >> 7;
    const int yi = bid & 127;

    qs[tid] = q[((size_t)xi * 128 + yi) * 256 + tid];
    __syncthreads();

    // --- score phase: thread tid owns z2 = tid (r half if <128, l half else),
    //     computes the dot for all 8 heads from one k row.
    const int z = tid & 127;
    const float* krow;
    if (tid < 128) krow = k + ((size_t)xi * 128 + tid) * 256; // k[x,z,:]
    else           krow = k + ((size_t)z * 128 + yi) * 256;   // k[z,y,:]

    float dot[NH];
#pragma unroll
    for (int h = 0; h < NH; h++) dot[h] = 0.0f;
    const float4* kr4 = (const float4*)krow;
#pragma unroll
    for (int c = 0; c < 64; c++) {
        float4 kv = kr4[c];
        float4 qv = *(const float4*)&qs[c * 4];
        dot[c >> 3] += kv.x * qv.x + kv.y * qv.y + kv.z * qv.z + kv.w * qv.w;
    }
    const int mk = mask[((size_t)xi * 128 + yi) * 128 + z];
    const float scale = 0.17677669529663687f; // 1/sqrt(32)
#pragma unroll
    for (int h = 0; h < NH; h++)
        sc[h][tid] = mk ? -1e9f : dot[h] * scale;
    __syncthreads();

    // --- softmax over 256 per head; 32 threads per head
    {
        const int h = tid >> 5;
        const int l = tid & 31;
        float vals[8];
        float mx = -3.0e38f;
#pragma unroll
        for (int t = 0; t < 8; t++) { vals[t] = sc[h][l + 32 * t]; mx = fmaxf(mx, vals[t]); }
#pragma unroll
        for (int d = 16; d >= 1; d >>= 1) mx = fmaxf(mx, __shfl_xor(mx, d));
        float sm = 0.0f;
#pragma unroll
        for (int t = 0; t < 8; t++) { vals[t] = __expf(vals[t] - mx); sm += vals[t]; }
#pragma unroll
        for (int d = 16; d >= 1; d >>= 1) sm += __shfl_xor(sm, d);
        float inv = 1.0f / sm;
#pragma unroll
        for (int t = 0; t < 8; t++) sc[h][l + 32 * t] = vals[t] * inv;
    }
    __syncthreads();

    // --- PV phase: thread tid = h*32 + d computes output channel tid
    const int h = tid >> 5;
    float acc = 0.0f;
#pragma unroll 4
    for (int zz = 0; zz < 128; zz++) {
        float ar = sc[h][zz];
        float al = sc[h][zz + 128];
        float vr = v[((size_t)xi * 128 + zz) * 256 + tid];
        float vl = v[((size_t)zz * 128 + yi) * 256 + tid];
        acc += ar * vr + al * vl;
    }
    xb[((size_t)xi * 128 + yi) * 256 + tid] = acc;
}

extern "C" void kernel_launch(void* const* d_in, const int* in_sizes, int n_in,
                              void* d_out, int out_size, void* d_ws, size_t ws_size,
                              hipStream_t stream) {
    const float* query = (const float*)d_in[0];
    const float* key_t = (const float*)d_in[1];
    const float* value = (const float*)d_in[2];
    const int*   mask  = (const int*)d_in[3];
    const float* Wq    = (const float*)d_in[4];
    const float* Wk    = (const float*)d_in[5];
    const float* Wv    = (const float*)d_in[6];
    const float* Wo    = (const float*)d_in[7];

    float* qb = (float*)d_ws;
    float* kb = qb + (size_t)M_ROWS * 256;
    float* vb = kb + (size_t)M_ROWS * 256;
    float* xb = vb + (size_t)M_ROWS * 256;

    dim3 gg(M_ROWS / 128, 256 / 128);
    gemm_bt_kernel<<<gg, 256, 0, stream>>>(query, Wq, qb);
    gemm_bt_kernel<<<gg, 256, 0, stream>>>(key_t, Wk, kb);
    gemm_bt_kernel<<<gg, 256, 0, stream>>>(value, Wv, vb);
    attn_kernel<<<M_ROWS, 256, 0, stream>>>(qb, kb, vb, mask, xb);
    gemm_bt_kernel<<<gg, 256, 0, stream>>>(xb, Wo, (float*)d_out);
}

// Round 2
// 327.037 us; speedup vs baseline: 2.8081x; 2.8081x over previous
//
#include <hip/hip_runtime.h>
#include <hip/hip_bf16.h>
#include <math.h>

#define N_DIM 128
#define NH 8
#define DKH 32
#define M_ROWS (N_DIM * N_DIM) // 16384

typedef __attribute__((ext_vector_type(8))) short bf16x8;
typedef __attribute__((ext_vector_type(4))) float f32x4;

__device__ inline ushort f2b(float x) {
    union { __hip_bfloat16 b; ushort u; } c;
    c.b = __float2bfloat16(x);
    return c.u;
}

// ---------------------------------------------------------------------------
// C[M][256] = A[M][256] @ W[256][256]^T, f32 in, f32 out (for final Wo gemm)
// ---------------------------------------------------------------------------
__global__ __launch_bounds__(256) void gemm_bt_kernel(const float* __restrict__ A,
                                                      const float* __restrict__ W,
                                                      float* __restrict__ C) {
    __shared__ alignas(16) float As[16][132];
    __shared__ alignas(16) float Bs[16][132];
    const int tid = threadIdx.x;
    const int row0 = blockIdx.x * 128;
    const int col0 = blockIdx.y * 128;
    const int tx = tid & 15;
    const int ty = tid >> 4;

    float acc[8][8];
#pragma unroll
    for (int i = 0; i < 8; i++)
#pragma unroll
        for (int j = 0; j < 8; j++) acc[i][j] = 0.0f;

    for (int k0 = 0; k0 < 256; k0 += 16) {
#pragma unroll
        for (int e = 0; e < 2; e++) {
            int idx = tid * 2 + e;
            int m = idx >> 2;
            int k4 = (idx & 3) * 4;
            float4 va = *(const float4*)(A + (size_t)(row0 + m) * 256 + k0 + k4);
            As[k4 + 0][m] = va.x; As[k4 + 1][m] = va.y;
            As[k4 + 2][m] = va.z; As[k4 + 3][m] = va.w;
            float4 vb = *(const float4*)(W + (size_t)(col0 + m) * 256 + k0 + k4);
            Bs[k4 + 0][m] = vb.x; Bs[k4 + 1][m] = vb.y;
            Bs[k4 + 2][m] = vb.z; Bs[k4 + 3][m] = vb.w;
        }
        __syncthreads();
#pragma unroll
        for (int k = 0; k < 16; k++) {
            float a[8], b[8];
            *(float4*)&a[0] = *(const float4*)&As[k][ty * 8];
            *(float4*)&a[4] = *(const float4*)&As[k][ty * 8 + 4];
            *(float4*)&b[0] = *(const float4*)&Bs[k][tx * 8];
            *(float4*)&b[4] = *(const float4*)&Bs[k][tx * 8 + 4];
#pragma unroll
            for (int i = 0; i < 8; i++)
#pragma unroll
                for (int j = 0; j < 8; j++) acc[i][j] += a[i] * b[j];
        }
        __syncthreads();
    }

#pragma unroll
    for (int i = 0; i < 8; i++) {
        float* cp = C + (size_t)(row0 + ty * 8 + i) * 256 + col0 + tx * 8;
        *(float4*)cp       = make_float4(acc[i][0], acc[i][1], acc[i][2], acc[i][3]);
        *(float4*)(cp + 4) = make_float4(acc[i][4], acc[i][5], acc[i][6], acc[i][7]);
    }
}

// ---------------------------------------------------------------------------
// Same GEMM but stores bf16 (q/k/v projections feed the MFMA attention)
// ---------------------------------------------------------------------------
__global__ __launch_bounds__(256) void gemm_bt_bf16(const float* __restrict__ A,
                                                    const float* __restrict__ W,
                                                    ushort* __restrict__ C) {
    __shared__ alignas(16) float As[16][132];
    __shared__ alignas(16) float Bs[16][132];
    const int tid = threadIdx.x;
    const int row0 = blockIdx.x * 128;
    const int col0 = blockIdx.y * 128;
    const int tx = tid & 15;
    const int ty = tid >> 4;

    float acc[8][8];
#pragma unroll
    for (int i = 0; i < 8; i++)
#pragma unroll
        for (int j = 0; j < 8; j++) acc[i][j] = 0.0f;

    for (int k0 = 0; k0 < 256; k0 += 16) {
#pragma unroll
        for (int e = 0; e < 2; e++) {
            int idx = tid * 2 + e;
            int m = idx >> 2;
            int k4 = (idx & 3) * 4;
            float4 va = *(const float4*)(A + (size_t)(row0 + m) * 256 + k0 + k4);
            As[k4 + 0][m] = va.x; As[k4 + 1][m] = va.y;
            As[k4 + 2][m] = va.z; As[k4 + 3][m] = va.w;
            float4 vb = *(const float4*)(W + (size_t)(col0 + m) * 256 + k0 + k4);
            Bs[k4 + 0][m] = vb.x; Bs[k4 + 1][m] = vb.y;
            Bs[k4 + 2][m] = vb.z; Bs[k4 + 3][m] = vb.w;
        }
        __syncthreads();
#pragma unroll
        for (int k = 0; k < 16; k++) {
            float a[8], b[8];
            *(float4*)&a[0] = *(const float4*)&As[k][ty * 8];
            *(float4*)&a[4] = *(const float4*)&As[k][ty * 8 + 4];
            *(float4*)&b[0] = *(const float4*)&Bs[k][tx * 8];
            *(float4*)&b[4] = *(const float4*)&Bs[k][tx * 8 + 4];
#pragma unroll
            for (int i = 0; i < 8; i++)
#pragma unroll
                for (int j = 0; j < 8; j++) acc[i][j] += a[i] * b[j];
        }
        __syncthreads();
    }

#pragma unroll
    for (int i = 0; i < 8; i++) {
        union { __hip_bfloat16 hh[8]; int4 v4; } u;
#pragma unroll
        for (int j = 0; j < 8; j++) u.hh[j] = __float2bfloat16(acc[i][j]);
        *(int4*)(C + (size_t)(row0 + ty * 8 + i) * 256 + col0 + tx * 8) = u.v4;
    }
}

// ---------------------------------------------------------------------------
// Attention pass. PASS=0: l-half, block=(y,h), rows are x.
//                 PASS=1: r-half + combine, block=(x,h), rows are y.
// S = Q K^T (128x128, K=32) via mfma 16x16x32 bf16; masked online softmax;
// P = exp(S-m) @ V (128x32, K=128). PASS0 stores m/s/P; PASS1 combines.
// ---------------------------------------------------------------------------
template <int PASS>
__global__ __launch_bounds__(256) void attn_pass(const ushort* __restrict__ qb,
                                                 const ushort* __restrict__ kb,
                                                 const ushort* __restrict__ vb,
                                                 const int* __restrict__ mask,
                                                 float* __restrict__ ml,
                                                 float* __restrict__ sl,
                                                 float* __restrict__ Pl,
                                                 float* __restrict__ xb) {
    __shared__ ushort Qs[128 * 32];   // row-major [row][d], 64B rows
    __shared__ ushort Ks[128 * 32];
    __shared__ ushort Vt[32 * 128];   // [d][z], 256B rows, XOR swizzled
    __shared__ ushort Ats[128 * 128]; // [row][z], 256B rows, XOR swizzled
    __shared__ float mlq[128], slq[128];

    const int tid = threadIdx.x;
    const int fixed = blockIdx.x >> 3; // y (PASS0) or x (PASS1)
    const int h = blockIdx.x & 7;

    int base, stride, mbase, mstride;
    if (PASS == 0) { // q[r(=x), fixed(=y), h, :]
        base = (fixed * NH + h) * DKH;
        stride = N_DIM * NH * DKH;
        mbase = fixed * N_DIM;        // mask[x=row][y=fixed][z=col]
        mstride = N_DIM * N_DIM;
    } else {         // q[fixed(=x), r(=y), h, :]
        base = fixed * N_DIM * NH * DKH + h * DKH;
        stride = NH * DKH;
        mbase = fixed * N_DIM * N_DIM; // mask[x=fixed][y=row][z=col]
        mstride = N_DIM;
    }

    if (PASS == 1) {
        if (tid < 128) mlq[tid] = ml[(tid * NH + h) * N_DIM + fixed];
        else           slq[tid - 128] = sl[((tid - 128) * NH + h) * N_DIM + fixed];
    }

    // ---- stage Q, K, Vt (transpose + swizzle) ----
#pragma unroll
    for (int i = 0; i < 2; i++) {
        int idx = tid + i * 256;
        int r = idx >> 2, d0 = (idx & 3) * 8;
        size_t goff = (size_t)base + (size_t)r * stride + d0;
        int4 qv = *(const int4*)(qb + goff);
        *(int4*)&Qs[r * 32 + d0] = qv;
        int4 kv = *(const int4*)(kb + goff);
        *(int4*)&Ks[r * 32 + d0] = kv;
        union { int4 v4; ushort u[8]; } uu;
        uu.v4 = *(const int4*)(vb + goff);
#pragma unroll
        for (int j = 0; j < 8; j++) {
            int d = d0 + j;
            int byte = d * 256 + r * 2;
            byte ^= (d & 7) << 4;
            Vt[byte >> 1] = uu.u[j];
        }
    }
    __syncthreads();

    const int w = tid >> 6;
    const int lane = tid & 63;
    const int lr = lane & 15;
    const int g = lane >> 4;
    const int rbase = w * 32;

    // ---- S = Q K^T ----
    bf16x8 aq[2];
#pragma unroll
    for (int fr = 0; fr < 2; fr++)
        aq[fr] = *(const bf16x8*)&Qs[(rbase + fr * 16 + lr) * 32 + g * 8];

    f32x4 s[2][8];
    const f32x4 zero = {0.f, 0.f, 0.f, 0.f};
#pragma unroll
    for (int fc = 0; fc < 8; fc++) {
        bf16x8 bk = *(const bf16x8*)&Ks[(fc * 16 + lr) * 32 + g * 8];
#pragma unroll
        for (int fr = 0; fr < 2; fr++)
            s[fr][fc] = __builtin_amdgcn_mfma_f32_16x16x32_bf16(aq[fr], bk, zero, 0, 0, 0);
    }

    // ---- mask, scale, row max, exp, row sum, att->LDS(bf16) ----
    const float scale = 0.17677669529663687f; // 1/sqrt(32)
    float mx[2][4], sm[2][4];
#pragma unroll
    for (int fr = 0; fr < 2; fr++) {
#pragma unroll
        for (int j = 0; j < 4; j++) {
            int row = rbase + fr * 16 + g * 4 + j;
            const int* mrow = mask + mbase + (size_t)row * mstride;
            float mmax = -3.0e38f;
#pragma unroll
            for (int fc = 0; fc < 8; fc++) {
                int col = fc * 16 + lr;
                float val = mrow[col] ? -1.0e9f : s[fr][fc][j] * scale;
                s[fr][fc][j] = val;
                mmax = fmaxf(mmax, val);
            }
            mmax = fmaxf(mmax, __shfl_xor(mmax, 1));
            mmax = fmaxf(mmax, __shfl_xor(mmax, 2));
            mmax = fmaxf(mmax, __shfl_xor(mmax, 4));
            mmax = fmaxf(mmax, __shfl_xor(mmax, 8));
            float ssum = 0.f;
#pragma unroll
            for (int fc = 0; fc < 8; fc++) {
                int col = fc * 16 + lr;
                float e = __expf(s[fr][fc][j] - mmax);
                ssum += e;
                int byte = row * 256 + col * 2;
                byte ^= (row & 7) << 4;
                Ats[byte >> 1] = f2b(e);
            }
            ssum += __shfl_xor(ssum, 1);
            ssum += __shfl_xor(ssum, 2);
            ssum += __shfl_xor(ssum, 4);
            ssum += __shfl_xor(ssum, 8);
            mx[fr][j] = mmax;
            sm[fr][j] = ssum;
        }
    }
    __syncthreads();

    // ---- P = att @ V ----
    f32x4 p[2][2];
    p[0][0] = zero; p[0][1] = zero; p[1][0] = zero; p[1][1] = zero;
#pragma unroll
    for (int ks = 0; ks < 4; ks++) {
        bf16x8 pa[2];
#pragma unroll
        for (int fr = 0; fr < 2; fr++) {
            int row = rbase + fr * 16 + lr;
            int byte = row * 256 + ks * 64 + g * 16;
            byte ^= (row & 7) << 4;
            pa[fr] = *(const bf16x8*)&Ats[byte >> 1];
        }
#pragma unroll
        for (int fc = 0; fc < 2; fc++) {
            int rd = fc * 16 + lr;
            int byte = rd * 256 + ks * 64 + g * 16;
            byte ^= (rd & 7) << 4;
            bf16x8 vbf = *(const bf16x8*)&Vt[byte >> 1];
#pragma unroll
            for (int fr = 0; fr < 2; fr++)
                p[fr][fc] = __builtin_amdgcn_mfma_f32_16x16x32_bf16(pa[fr], vbf, p[fr][fc], 0, 0, 0);
        }
    }

    // ---- epilogue ----
    if (PASS == 0) {
#pragma unroll
        for (int fr = 0; fr < 2; fr++) {
#pragma unroll
            for (int j = 0; j < 4; j++) {
                int row = rbase + fr * 16 + g * 4 + j;
                if (lr == 0) {
                    ml[(fixed * NH + h) * N_DIM + row] = mx[fr][j];
                    sl[(fixed * NH + h) * N_DIM + row] = sm[fr][j];
                }
#pragma unroll
                for (int fc = 0; fc < 2; fc++) {
                    int d = fc * 16 + lr;
                    Pl[((size_t)(fixed * NH + h) * N_DIM + row) * DKH + d] = p[fr][fc][j];
                }
            }
        }
    } else {
#pragma unroll
        for (int fr = 0; fr < 2; fr++) {
#pragma unroll
            for (int j = 0; j < 4; j++) {
                int row = rbase + fr * 16 + g * 4 + j;
                float mr = mx[fr][j], sr = sm[fr][j];
                float mlv = mlq[row], slv = slq[row];
                float m = fmaxf(mr, mlv);
                float cr = __expf(mr - m), cl = __expf(mlv - m);
                float inv = 1.0f / (sr * cr + slv * cl);
#pragma unroll
                for (int fc = 0; fc < 2; fc++) {
                    int d = fc * 16 + lr;
                    float plv = Pl[((size_t)(row * NH + h) * N_DIM + fixed) * DKH + d];
                    float o = (p[fr][fc][j] * cr + plv * cl) * inv;
                    xb[((size_t)fixed * N_DIM + row) * 256 + h * DKH + d] = o;
                }
            }
        }
    }
}

extern "C" void kernel_launch(void* const* d_in, const int* in_sizes, int n_in,
                              void* d_out, int out_size, void* d_ws, size_t ws_size,
                              hipStream_t stream) {
    const float* query = (const float*)d_in[0];
    const float* key_t = (const float*)d_in[1];
    const float* value = (const float*)d_in[2];
    const int*   mask  = (const int*)d_in[3];
    const float* Wq    = (const float*)d_in[4];
    const float* Wk    = (const float*)d_in[5];
    const float* Wv    = (const float*)d_in[6];
    const float* Wo    = (const float*)d_in[7];

    char* ws = (char*)d_ws;
    ushort* qb = (ushort*)ws;                           // 8 MB
    ushort* kb = (ushort*)(ws + (size_t)8 * 1024 * 1024);
    ushort* vb = (ushort*)(ws + (size_t)16 * 1024 * 1024);
    float*  ml = (float*)(ws + (size_t)24 * 1024 * 1024);   // 512 KB
    float*  sl = (float*)(ws + (size_t)25 * 1024 * 1024);   // 512 KB
    float*  Pl = (float*)(ws + (size_t)26 * 1024 * 1024);   // 16 MB
    float*  xb = (float*)(ws + (size_t)42 * 1024 * 1024);   // 16 MB

    dim3 gg(M_ROWS / 128, 2);
    gemm_bt_bf16<<<gg, 256, 0, stream>>>(query, Wq, qb);
    gemm_bt_bf16<<<gg, 256, 0, stream>>>(key_t, Wk, kb);
    gemm_bt_bf16<<<gg, 256, 0, stream>>>(value, Wv, vb);
    attn_pass<0><<<N_DIM * NH, 256, 0, stream>>>(qb, kb, vb, mask, ml, sl, Pl, xb);
    attn_pass<1><<<N_DIM * NH, 256, 0, stream>>>(qb, kb, vb, mask, ml, sl, Pl, xb);
    gemm_bt_kernel<<<gg, 256, 0, stream>>>(xb, Wo, (float*)d_out);
}

// Round 4
// 187.078 us; speedup vs baseline: 4.9089x; 1.7481x over previous
//
#include <hip/hip_runtime.h>
#include <hip/hip_bf16.h>
#include <math.h>

#define N_DIM 128
#define NH 8
#define DKH 32
#define M_ROWS (N_DIM * N_DIM) // 16384

typedef __attribute__((ext_vector_type(8))) short bf16x8;
typedef __attribute__((ext_vector_type(4))) float f32x4;

__device__ inline ushort f2b(float x) {
    union { __hip_bfloat16 b; ushort u; } c;
    c.b = __float2bfloat16(x);
    return c.u;
}

#define GLDS(src, dst) \
    __builtin_amdgcn_global_load_lds((const __attribute__((address_space(1))) void*)(src), \
                                     (__attribute__((address_space(3))) void*)(dst), 16, 0, 0)

// ---------------------------------------------------------------------------
// Convert the four 256x256 f32 weight matrices to bf16 (packed [4][65536])
// ---------------------------------------------------------------------------
__global__ __launch_bounds__(256) void cvt_w_kernel(const float* __restrict__ w0,
                                                    const float* __restrict__ w1,
                                                    const float* __restrict__ w2,
                                                    const float* __restrict__ w3,
                                                    ushort* __restrict__ out) {
    const int b = blockIdx.x;          // 0..255
    const int m = b >> 6;
    const float* src = (m == 0) ? w0 : (m == 1) ? w1 : (m == 2) ? w2 : w3;
    const int off = (b & 63) * 1024 + threadIdx.x * 4;
    float4 v = *(const float4*)(src + off);
    union { ushort u[4]; short4 s4; } p;
    p.u[0] = f2b(v.x); p.u[1] = f2b(v.y); p.u[2] = f2b(v.z); p.u[3] = f2b(v.w);
    *(short4*)(out + (size_t)m * 65536 + off) = p.s4;
}

// ---------------------------------------------------------------------------
// C[M][256] = A[M][256] @ W[256][256]^T via mfma 16x16x32 bf16.
// BM=64, BN=256 (full), BK=32, 512 threads = 8 waves (4M x 2N), dbuf LDS.
// ABF16: A already bf16 (use global_load_lds). else f32 -> cvt in regs.
// OBF16: store bf16, else f32.
// ---------------------------------------------------------------------------
template <bool ABF16, bool OBF16>
__global__ __launch_bounds__(512) void gemm_mfma(const void* __restrict__ Ain,
                                                 const ushort* __restrict__ Wb,
                                                 void* __restrict__ Cout) {
    __shared__ ushort As[2][64 * 32];   // 4 KB per buf
    __shared__ ushort Ws[2][256 * 32];  // 16 KB per buf
    const int tid = threadIdx.x;
    const int row0 = blockIdx.x * 64;
    const int w = tid >> 6, lane = tid & 63;
    const int lr = lane & 15, g = lane >> 4;
    const int wm = w & 3, wn = w >> 2;

    auto stage = [&](int t, int buf) {
        const int kbase = t * 32;
        // W rows: 16 chunks of 16 rows, chunk c -> LDS bytes [c*1024, +1024)
#pragma unroll
        for (int i = 0; i < 2; i++) {
            int c = i * 8 + w;
            const ushort* src = Wb + (size_t)(c * 16 + (lane >> 2)) * 256 + kbase + (lane & 3) * 8;
            GLDS(src, &Ws[buf][c * 512]);
        }
        if (ABF16) {
            if (tid < 256) { // waves 0..3, chunk = wave
                const ushort* Ab = (const ushort*)Ain;
                const ushort* src = Ab + (size_t)(row0 + w * 16 + (lane >> 2)) * 256 + kbase + (lane & 3) * 8;
                GLDS(src, &As[buf][w * 512]);
            }
        } else {
            const float* Af = (const float*)Ain;
            const int r = tid >> 3, k0 = (tid & 7) * 4;
            float4 v = *(const float4*)(Af + (size_t)(row0 + r) * 256 + kbase + k0);
            union { ushort u[4]; short4 s4; } p;
            p.u[0] = f2b(v.x); p.u[1] = f2b(v.y); p.u[2] = f2b(v.z); p.u[3] = f2b(v.w);
            *(short4*)&As[buf][r * 32 + k0] = p.s4;
        }
    };

    f32x4 acc[8];
    const f32x4 zero = {0.f, 0.f, 0.f, 0.f};
#pragma unroll
    for (int fc = 0; fc < 8; fc++) acc[fc] = zero;

    stage(0, 0);
    __syncthreads();

#pragma unroll
    for (int t = 0; t < 8; t++) {
        const int cur = t & 1;
        if (t < 7) stage(t + 1, cur ^ 1);
        bf16x8 aq = *(const bf16x8*)&As[cur][(wm * 16 + lr) * 32 + g * 8];
#pragma unroll
        for (int fc = 0; fc < 8; fc++) {
            bf16x8 bw = *(const bf16x8*)&Ws[cur][(wn * 128 + fc * 16 + lr) * 32 + g * 8];
            acc[fc] = __builtin_amdgcn_mfma_f32_16x16x32_bf16(aq, bw, acc[fc], 0, 0, 0);
        }
        __syncthreads();
    }

#pragma unroll
    for (int fc = 0; fc < 8; fc++) {
#pragma unroll
        for (int j = 0; j < 4; j++) {
            const int row = row0 + wm * 16 + g * 4 + j;
            const int col = wn * 128 + fc * 16 + lr;
            if (OBF16) ((ushort*)Cout)[(size_t)row * 256 + col] = f2b(acc[fc][j]);
            else       ((float*)Cout)[(size_t)row * 256 + col] = acc[fc][j];
        }
    }
}

// ---------------------------------------------------------------------------
// Attention pass. PASS=0: l-half, block=(y,h), rows are x.
//                 PASS=1: r-half + combine, block=(x,h), rows are y.
// ---------------------------------------------------------------------------
template <int PASS>
__global__ __launch_bounds__(256) void attn_pass(const ushort* __restrict__ qb,
                                                 const ushort* __restrict__ kb,
                                                 const ushort* __restrict__ vb,
                                                 const int* __restrict__ mask,
                                                 float* __restrict__ ml,
                                                 float* __restrict__ sl,
                                                 float* __restrict__ Pl,
                                                 ushort* __restrict__ xb) {
    __shared__ ushort Qs[128 * 32];   // row-major [row][d], 64B rows
    __shared__ ushort Ks[128 * 32];
    __shared__ ushort Vt[32 * 128];   // [d][z], 256B rows, XOR swizzled
    __shared__ ushort Ats[128 * 128]; // [row][z], 256B rows, XOR swizzled
    __shared__ float mlq[128], slq[128];

    const int tid = threadIdx.x;
    const int fixed = blockIdx.x >> 3; // y (PASS0) or x (PASS1)
    const int h = blockIdx.x & 7;

    int base, stride, mbase, mstride;
    if (PASS == 0) {
        base = (fixed * NH + h) * DKH;
        stride = N_DIM * NH * DKH;
        mbase = fixed * N_DIM;
        mstride = N_DIM * N_DIM;
    } else {
        base = fixed * N_DIM * NH * DKH + h * DKH;
        stride = NH * DKH;
        mbase = fixed * N_DIM * N_DIM;
        mstride = N_DIM;
    }

    if (PASS == 1) {
        if (tid < 128) mlq[tid] = ml[(tid * NH + h) * N_DIM + fixed];
        else           slq[tid - 128] = sl[((tid - 128) * NH + h) * N_DIM + fixed];
    }

    // ---- stage Q, K, Vt (transpose + swizzle) ----
#pragma unroll
    for (int i = 0; i < 2; i++) {
        int idx = tid + i * 256;
        int r = idx >> 2, d0 = (idx & 3) * 8;
        size_t goff = (size_t)base + (size_t)r * stride + d0;
        int4 qv = *(const int4*)(qb + goff);
        *(int4*)&Qs[r * 32 + d0] = qv;
        int4 kv = *(const int4*)(kb + goff);
        *(int4*)&Ks[r * 32 + d0] = kv;
        union { int4 v4; ushort u[8]; } uu;
        uu.v4 = *(const int4*)(vb + goff);
#pragma unroll
        for (int j = 0; j < 8; j++) {
            int d = d0 + j;
            int byte = d * 256 + r * 2;
            byte ^= (d & 7) << 4;
            Vt[byte >> 1] = uu.u[j];
        }
    }
    __syncthreads();

    const int w = tid >> 6;
    const int lane = tid & 63;
    const int lr = lane & 15;
    const int g = lane >> 4;
    const int rbase = w * 32;

    // ---- S = Q K^T ----
    bf16x8 aq[2];
#pragma unroll
    for (int fr = 0; fr < 2; fr++)
        aq[fr] = *(const bf16x8*)&Qs[(rbase + fr * 16 + lr) * 32 + g * 8];

    f32x4 s[2][8];
    const f32x4 zero = {0.f, 0.f, 0.f, 0.f};
#pragma unroll
    for (int fc = 0; fc < 8; fc++) {
        bf16x8 bk = *(const bf16x8*)&Ks[(fc * 16 + lr) * 32 + g * 8];
#pragma unroll
        for (int fr = 0; fr < 2; fr++)
            s[fr][fc] = __builtin_amdgcn_mfma_f32_16x16x32_bf16(aq[fr], bk, zero, 0, 0, 0);
    }

    // ---- mask, scale, row max, exp, row sum, att->LDS(bf16) ----
    const float scale = 0.17677669529663687f; // 1/sqrt(32)
    float mx[2][4], sm[2][4];
#pragma unroll
    for (int fr = 0; fr < 2; fr++) {
#pragma unroll
        for (int j = 0; j < 4; j++) {
            int row = rbase + fr * 16 + g * 4 + j;
            const int* mrow = mask + mbase + (size_t)row * mstride;
            float mmax = -3.0e38f;
#pragma unroll
            for (int fc = 0; fc < 8; fc++) {
                int col = fc * 16 + lr;
                float val = mrow[col] ? -1.0e9f : s[fr][fc][j] * scale;
                s[fr][fc][j] = val;
                mmax = fmaxf(mmax, val);
            }
            mmax = fmaxf(mmax, __shfl_xor(mmax, 1));
            mmax = fmaxf(mmax, __shfl_xor(mmax, 2));
            mmax = fmaxf(mmax, __shfl_xor(mmax, 4));
            mmax = fmaxf(mmax, __shfl_xor(mmax, 8));
            float ssum = 0.f;
#pragma unroll
            for (int fc = 0; fc < 8; fc++) {
                int col = fc * 16 + lr;
                float e = __expf(s[fr][fc][j] - mmax);
                ssum += e;
                int byte = row * 256 + col * 2;
                byte ^= (row & 7) << 4;
                Ats[byte >> 1] = f2b(e);
            }
            ssum += __shfl_xor(ssum, 1);
            ssum += __shfl_xor(ssum, 2);
            ssum += __shfl_xor(ssum, 4);
            ssum += __shfl_xor(ssum, 8);
            mx[fr][j] = mmax;
            sm[fr][j] = ssum;
        }
    }
    __syncthreads();

    // ---- P = att @ V ----
    f32x4 p[2][2];
    p[0][0] = zero; p[0][1] = zero; p[1][0] = zero; p[1][1] = zero;
#pragma unroll
    for (int ks = 0; ks < 4; ks++) {
        bf16x8 pa[2];
#pragma unroll
        for (int fr = 0; fr < 2; fr++) {
            int row = rbase + fr * 16 + lr;
            int byte = row * 256 + ks * 64 + g * 16;
            byte ^= (row & 7) << 4;
            pa[fr] = *(const bf16x8*)&Ats[byte >> 1];
        }
#pragma unroll
        for (int fc = 0; fc < 2; fc++) {
            int rd = fc * 16 + lr;
            int byte = rd * 256 + ks * 64 + g * 16;
            byte ^= (rd & 7) << 4;
            bf16x8 vbf = *(const bf16x8*)&Vt[byte >> 1];
#pragma unroll
            for (int fr = 0; fr < 2; fr++)
                p[fr][fc] = __builtin_amdgcn_mfma_f32_16x16x32_bf16(pa[fr], vbf, p[fr][fc], 0, 0, 0);
        }
    }

    // ---- epilogue ----
    if (PASS == 0) {
#pragma unroll
        for (int fr = 0; fr < 2; fr++) {
#pragma unroll
            for (int j = 0; j < 4; j++) {
                int row = rbase + fr * 16 + g * 4 + j;
                if (lr == 0) {
                    ml[(fixed * NH + h) * N_DIM + row] = mx[fr][j];
                    sl[(fixed * NH + h) * N_DIM + row] = sm[fr][j];
                }
#pragma unroll
                for (int fc = 0; fc < 2; fc++) {
                    int d = fc * 16 + lr;
                    Pl[((size_t)(fixed * NH + h) * N_DIM + row) * DKH + d] = p[fr][fc][j];
                }
            }
        }
    } else {
#pragma unroll
        for (int fr = 0; fr < 2; fr++) {
#pragma unroll
            for (int j = 0; j < 4; j++) {
                int row = rbase + fr * 16 + g * 4 + j;
                float mr = mx[fr][j], sr = sm[fr][j];
                float mlv = mlq[row], slv = slq[row];
                float m = fmaxf(mr, mlv);
                float cr = __expf(mr - m), cl = __expf(mlv - m);
                float inv = 1.0f / (sr * cr + slv * cl);
#pragma unroll
                for (int fc = 0; fc < 2; fc++) {
                    int d = fc * 16 + lr;
                    float plv = Pl[((size_t)(row * NH + h) * N_DIM + fixed) * DKH + d];
                    float o = (p[fr][fc][j] * cr + plv * cl) * inv;
                    xb[((size_t)fixed * N_DIM + row) * 256 + h * DKH + d] = f2b(o);
                }
            }
        }
    }
}

extern "C" void kernel_launch(void* const* d_in, const int* in_sizes, int n_in,
                              void* d_out, int out_size, void* d_ws, size_t ws_size,
                              hipStream_t stream) {
    const float* query = (const float*)d_in[0];
    const float* key_t = (const float*)d_in[1];
    const float* value = (const float*)d_in[2];
    const int*   mask  = (const int*)d_in[3];
    const float* Wq    = (const float*)d_in[4];
    const float* Wk    = (const float*)d_in[5];
    const float* Wv    = (const float*)d_in[6];
    const float* Wo    = (const float*)d_in[7];

    char* ws = (char*)d_ws;
    ushort* qb = (ushort*)ws;                                  // 8 MB
    ushort* kb = (ushort*)(ws + (size_t)8 * 1024 * 1024);      // 8 MB
    ushort* vb = (ushort*)(ws + (size_t)16 * 1024 * 1024);     // 8 MB
    float*  ml = (float*)(ws + (size_t)24 * 1024 * 1024);      // 512 KB
    float*  sl = (float*)(ws + (size_t)25 * 1024 * 1024);      // 512 KB
    float*  Pl = (float*)(ws + (size_t)26 * 1024 * 1024);      // 16 MB
    ushort* xb = (ushort*)(ws + (size_t)42 * 1024 * 1024);     // 8 MB
    ushort* Wb = (ushort*)(ws + (size_t)50 * 1024 * 1024);     // 512 KB

    cvt_w_kernel<<<256, 256, 0, stream>>>(Wq, Wk, Wv, Wo, Wb);
    gemm_mfma<false, true><<<M_ROWS / 64, 512, 0, stream>>>(query, Wb + 0 * 65536, qb);
    gemm_mfma<false, true><<<M_ROWS / 64, 512, 0, stream>>>(key_t, Wb + 1 * 65536, kb);
    gemm_mfma<false, true><<<M_ROWS / 64, 512, 0, stream>>>(value, Wb + 2 * 65536, vb);
    attn_pass<0><<<N_DIM * NH, 256, 0, stream>>>(qb, kb, vb, mask, ml, sl, Pl, xb);
    attn_pass<1><<<N_DIM * NH, 256, 0, stream>>>(qb, kb, vb, mask, ml, sl, Pl, xb);
    gemm_mfma<true, false><<<M_ROWS / 64, 512, 0, stream>>>(xb, Wb + 3 * 65536, (float*)d_out);
}